// Round 2
// baseline (899.277 us; speedup 1.0000x reference)
//
#include <hip/hip_runtime.h>

// Problem constants
#define H   512
#define W   512
#define C   256
#define KH  11
#define KW  11
#define OH  502
#define OW  502
#define OUT_MAP (OH * OW)   // 252004
#define HWSZ (H * W)

// Tiling: 256 threads as 16x16; each thread computes TY x TX = 2x8 outputs.
// TY=2 -> weight rolling window is only 2 rows (24 VGPR) and each weight row
// is ds_read exactly once per channel (no 4x redundancy of the 4x4 tiling).
#define TX 8
#define TY 2
#define TILE_X 128           // 16 threads * 8
#define TILE_Y 32            // 16 threads * 2
#define IN_Y  (TILE_Y + KH - 1)    // 42
#define UPR   35                   // 16B units per LDS row (140 floats >= 138)
#define IN_XP (UPR * 4)            // 140 floats
#define CPB   16                   // grid 4x16x16 = 1024 blocks = 4/CU exact
#define NSTAGE_TOT (IN_Y * UPR)    // 1470 float4 slots
#define NSTAGE_IT  6               // ceil(1470/256)
#define WPC 132                    // weights per channel in LDS: 11 rows x 12 padded

// Unit swizzle (16B units within a row): XOR an odd bit so the stride-2-unit
// read pattern of TX=8 (even units only -> 4-way bank conflict) spreads over
// all 8 bank-quads. Bijective on [0,35); keeps linear staging writes conflict-free.
__device__ __forceinline__ int swz(int u) { return u ^ ((u >> 3) & 1); }

// Static component selectors — fold to plain registers under full unroll.
#define AV(j)   ((j & 3) == 0 ? av[(j) >> 2].x : (j & 3) == 1 ? av[(j) >> 2].y : \
                 (j & 3) == 2 ? av[(j) >> 2].z : av[(j) >> 2].w)
#define WVS(q, j) ((j & 3) == 0 ? q[(j) >> 2].x : (j & 3) == 1 ? q[(j) >> 2].y : \
                   (j & 3) == 2 ? q[(j) >> 2].z : q[(j) >> 2].w)

__global__ __launch_bounds__(256, 4)
void conv_kernel(const float* __restrict__ x, const float* __restrict__ w,
                 float* __restrict__ out)
{
    __shared__ float s_in[IN_Y * IN_XP];    // 23520 B
    __shared__ float s_w[CPB * WPC];        // 8448 B -> total 31.2 KB, 4 blocks/CU

    const int tid = threadIdx.x;
    const int tx  = tid & 15;
    const int ty  = tid >> 4;
    const int x0  = blockIdx.x * TILE_X;
    const int y0  = blockIdx.y * TILE_Y;
    const int c0  = blockIdx.z * CPB;

    // ---- weights -> LDS once per block, repacked [ch][kh][12] (16B-aligned rows).
    // In the compute loop weights become broadcast ds_read_b128: in-order LGKM,
    // no SMEM/VMEM mixing -> compiler can fine-count lgkmcnt and keep the
    // ds_read pipeline running (the round-1 stall source).
    for (int it = tid; it < CPB * 121; it += 256) {
        const int ch  = it / 121;
        const int rem = it - ch * 121;
        const int kh  = rem / 11;
        const int kw  = rem - kh * 11;
        s_w[ch * WPC + kh * 12 + kw] = w[(size_t)(c0 + ch) * 121 + rem];
    }

    // ---- channel-invariant staging descriptors (clamped; garbage cells only
    // feed out-of-range outputs which are discarded at the epilogue) ----
    int s_goff[NSTAGE_IT], s_loff[NSTAGE_IT];
#pragma unroll
    for (int j = 0; j < NSTAGE_IT; ++j) {
        int i = tid + j * 256;
        if (i >= NSTAGE_TOT) i = NSTAGE_TOT - 1;   // dup write, same value: benign
        const int row = i / UPR;
        const int vec = i - row * UPR;
        const int gy  = min(y0 + row, H - 1);
        const int gx  = min(x0 + vec * 4, W - 4);
        s_goff[j] = gy * W + gx;
        s_loff[j] = row * IN_XP + swz(vec) * 4;
    }

    float acc[TY][TX];
#pragma unroll
    for (int dy = 0; dy < TY; ++dy)
#pragma unroll
        for (int i = 0; i < TX; ++i) acc[dy][i] = 0.f;

    const int ry0  = ty * TY;
    const int cx0u = tx * 2;             // 16B-unit column base
    int roff[5];                          // swizzled read offsets, channel-invariant
#pragma unroll
    for (int k = 0; k < 5; ++k) roff[k] = swz(cx0u + k) * 4;

    // ---- register prefetch of channel c0 (both batches) ----
    float4 pa[NSTAGE_IT], pb[NSTAGE_IT];
    {
        const float* __restrict__ p0 = x + (size_t)c0 * HWSZ;
        const float* __restrict__ p1 = p0 + (size_t)C * HWSZ;
#pragma unroll
        for (int j = 0; j < NSTAGE_IT; ++j) {
            pa[j] = *(const float4*)(p0 + s_goff[j]);
            pb[j] = *(const float4*)(p1 + s_goff[j]);
        }
    }

#pragma unroll 1
    for (int cc = 0; cc < CPB; ++cc) {
        // ---- drain prefetched regs: batch-sum and write tile to LDS ----
#pragma unroll
        for (int j = 0; j < NSTAGE_IT; ++j)
            *(float4*)&s_in[s_loff[j]] =
                make_float4(pa[j].x + pb[j].x, pa[j].y + pb[j].y,
                            pa[j].z + pb[j].z, pa[j].w + pb[j].w);
        __syncthreads();

        // ---- issue next channel's loads inside the compute window; the only
        // vmcnt wait left is the compiler's drain before the closing barrier,
        // ~4000 FMA cycles after issue. ----
        if (cc + 1 < CPB) {
            const float* __restrict__ p0 = x + (size_t)(c0 + cc + 1) * HWSZ;
            const float* __restrict__ p1 = p0 + (size_t)C * HWSZ;
#pragma unroll
            for (int j = 0; j < NSTAGE_IT; ++j) {
                pa[j] = *(const float4*)(p0 + s_goff[j]);
                pb[j] = *(const float4*)(p1 + s_goff[j]);
            }
        }

        // ---- compute: 12 input rows; weight rows enter a 2-deep rolling
        // register window (read once each, broadcast b128 from LDS) ----
        const float* __restrict__ swc = s_w + cc * WPC;
        float4 wr[2][3];                 // [parity][3 x float4 = 12 floats]
#pragma unroll
        for (int r = 0; r < TY + KH - 1; ++r) {      // 12 rows
            const float* rp = &s_in[(ry0 + r) * IN_XP];
            float4 av[5];
#pragma unroll
            for (int k = 0; k < 5; ++k)
                av[k] = *(const float4*)(rp + roff[k]);

            if (r < KH) {                // weight row kh = r enters the window
                const float* wrow = swc + r * 12;
                wr[r & 1][0] = *(const float4*)(wrow + 0);
                wr[r & 1][1] = *(const float4*)(wrow + 4);
                wr[r & 1][2] = *(const float4*)(wrow + 8);
            }

            if (r < KH) {                // dy = 0 uses kh = r
#pragma unroll
                for (int kw = 0; kw < KW; ++kw) {
                    const float wv = WVS(wr[r & 1], kw);
#pragma unroll
                    for (int i = 0; i < TX; ++i)
                        acc[0][i] += AV(kw + i) * wv;
                }
            }
            if (r >= 1) {                // dy = 1 uses kh = r - 1
#pragma unroll
                for (int kw = 0; kw < KW; ++kw) {
                    const float wv = WVS(wr[(r - 1) & 1], kw);
#pragma unroll
                    for (int i = 0; i < TX; ++i)
                        acc[1][i] += AV(kw + i) * wv;
                }
            }
        }
        __syncthreads();
    }

    // ---- accumulate partials into bias-initialized output (batch 0 map) ----
#pragma unroll
    for (int dy = 0; dy < TY; ++dy) {
        const int oy = y0 + ry0 + dy;
        if (oy < OH) {
#pragma unroll
            for (int i = 0; i < TX; ++i) {
                const int ox = x0 + tx * TX + i;
                if (ox < OW)
                    atomicAdd(&out[(size_t)oy * OW + ox], acc[dy][i]);
            }
        }
    }
}

__global__ void init_kernel(float* __restrict__ out, const float* __restrict__ bias)
{
    const int i = blockIdx.x * 256 + threadIdx.x;
    if (i < OUT_MAP) out[i] = bias[0];
}

__global__ void bcast_kernel(float* __restrict__ out)
{
    const int i = blockIdx.x * 256 + threadIdx.x;
    if (i < OUT_MAP) out[OUT_MAP + i] = out[i];
}

extern "C" void kernel_launch(void* const* d_in, const int* in_sizes, int n_in,
                              void* d_out, int out_size, void* d_ws, size_t ws_size,
                              hipStream_t stream)
{
    const float* x    = (const float*)d_in[0];   // (2,256,512,512) fp32
    const float* w    = (const float*)d_in[1];   // (1,256,11,11)  fp32
    const float* bias = (const float*)d_in[2];   // (1,)           fp32
    float* out = (float*)d_out;                  // (2,1,502,502)  fp32

    const int nb = (OUT_MAP + 255) / 256;
    init_kernel<<<nb, 256, 0, stream>>>(out, bias);
    conv_kernel<<<dim3(4, 16, 16), 256, 0, stream>>>(x, w, out);
    bcast_kernel<<<nb, 256, 0, stream>>>(out);
}